// Round 17
// baseline (237.852 us; speedup 1.0000x reference)
//
#include <hip/hip_runtime.h>
#include <hip/hip_fp16.h>

typedef _Float16 f16;
typedef _Float16 f16x8 __attribute__((ext_vector_type(8)));
typedef float f32x4 __attribute__((ext_vector_type(4)));

constexpr int C = 128;        // channels
constexpr int V = 65536;      // voxels
constexpr int PTS = 64;       // points per MFMA tile
constexpr int MLP_BLOCK = 512;// 8 waves; each wave owns 16 output channels
constexpr int BKT = 64;       // bucket capacity per voxel (P(overflow) ~ 1e-26)
constexpr size_t MLP_LDS = 80 * 1024;  // fstage 32K | os 16K | f 16K | h 16K

union U16 { uint4 u; f16x8 h; };

// async global->LDS, 16B/lane; LDS dest = wave-uniform base + lane*16.
__device__ __forceinline__ void gll16(const void* g, void* l) {
    auto gp = (const __attribute__((address_space(1))) unsigned int*)(unsigned long long)(uintptr_t)g;
    auto lp = (__attribute__((address_space(3))) unsigned int*)(unsigned int)(uintptr_t)l;
    __builtin_amdgcn_global_load_lds(gp, lp, 16, 0, 0);
}

// Barrier that does NOT drain vmcnt (GLLs stay in flight across it).
// Only LDS ordering is needed at these barriers -> lgkmcnt(0) suffices.
__device__ __forceinline__ void bar_lds() {
    asm volatile("s_waitcnt lgkmcnt(0)" ::: "memory");
    __builtin_amdgcn_s_barrier();
    asm volatile("" ::: "memory");
}

// -------------------------------------------------------------------------
// Kernel 0: zero the counters (rocclr's small fill kernel is latency-bound).
// -------------------------------------------------------------------------
__global__ void zero_cnt(int4* __restrict__ cnt) {
    const int t = blockIdx.x * blockDim.x + threadIdx.x;
    cnt[t] = make_int4(0, 0, 0, 0);
}

// -------------------------------------------------------------------------
// Kernel 1: bucket scatter — fixed-stride CSR, no scan needed.
// -------------------------------------------------------------------------
__global__ void bucket_scatter(const int* __restrict__ idx, int* __restrict__ cnt,
                               int* __restrict__ bucket, int n) {
    const int t = blockIdx.x * blockDim.x + threadIdx.x;
    if (t < n) {
        const int v = idx[t];
        const int slot = atomicAdd(&cnt[v], 1);
        if (slot < BKT) bucket[(v << 6) + slot] = t;
    }
}

// -------------------------------------------------------------------------
// Kernel 2: pooling — one wave per voxel; half-wave per point row, float4
// loads (32 lanes x 16B = 512B row), 2-deep unroll -> 4 rows in flight.
// -------------------------------------------------------------------------
__global__ void __launch_bounds__(256)
pool_bucket(const float* __restrict__ feats, const int* __restrict__ bucket,
            const int* __restrict__ cnt, __half* __restrict__ pooled) {
    const int v = blockIdx.x * 4 + (threadIdx.x >> 6);
    const int lane = threadIdx.x & 63;
    const int half = lane >> 5;      // 0 or 1: which point of a pair
    const int l32 = lane & 31;       // channel quad: channels l32*4..+3
    const int e = min(cnt[v], BKT);
    const int* b = bucket + (v << 6);

    f32x4 a0 = {0.f, 0.f, 0.f, 0.f};
    f32x4 a1 = {0.f, 0.f, 0.f, 0.f};
    int j = half;
    for (; j + 2 < e; j += 4) {      // handles rows j and j+2 per iter
        const int p0 = b[j];
        const int p1 = b[j + 2];
        a0 += *reinterpret_cast<const f32x4*>(feats + (size_t)p0 * C + l32 * 4);
        a1 += *reinterpret_cast<const f32x4*>(feats + (size_t)p1 * C + l32 * 4);
    }
    if (j < e) {
        const int p0 = b[j];
        a0 += *reinterpret_cast<const f32x4*>(feats + (size_t)p0 * C + l32 * 4);
    }
    a0 += a1;
#pragma unroll
    for (int c = 0; c < 4; ++c)
        a0[c] += __shfl_xor(a0[c], 32);

    if (half == 0) {
        const float rc = e ? 1.0f / (float)e : 0.f;
        const __half2 lo = __floats2half2_rn(a0[0] * rc, a0[1] * rc);
        const __half2 hi = __floats2half2_rn(a0[2] * rc, a0[3] * rc);
        union { uint2 u; __half2 h[2]; } pk;
        pk.h[0] = lo; pk.h[1] = hi;
        *reinterpret_cast<uint2*>(pooled + (size_t)v * C + l32 * 4) = pk.u;
    }
}

// -------------------------------------------------------------------------
// Kernel 3: fused gather + 2-layer MLP via f16 MFMA (16x16x32).
// R13 skeleton (8 waves x 16 ch, VGPR ~100 = 16 waves/CU). Latency fixes
// that cost ~0 registers (R15/R16's +17-reg prefetch crossed the 128 cliff):
//  - feats for tile i+1 DMA'd via global_load_lds into a 32 KB fstage
//    (wave-private slots); LDS 48->80 KB leaves 2 blocks/CU unchanged
//    (VGPR is the binding limit, not LDS — unlike R11's 4-wave skeleton).
//  - idx prefetched 1 tile ahead (1 persistent VGPR) so the stage's only
//    exposed latency is the L2-hot pooled gather (~300 cy, was ~1200).
//  - non-draining barriers keep the DMA in flight; explicit vmcnt(0) before
//    fstage reads covers the GLL->ds_read dependency; sched_barrier pins
//    GLL issue after the fstage reads it would otherwise race with.
// -------------------------------------------------------------------------
__global__ void __launch_bounds__(MLP_BLOCK)
mlp_mfma(const float* __restrict__ feats,
         const float* __restrict__ W1g,
         const float* __restrict__ b1g,
         const float* __restrict__ W2g,
         const float* __restrict__ b2g,
         const int* __restrict__ idx,
         const __half* __restrict__ pooled,
         float* __restrict__ out,
         int n) {
    extern __shared__ char smem[];
    char* fstage = smem;                 // 32 KB: chunk c at c*8192 + t*16
    char* os_b   = smem + 32768;         // 16 KB f16, XOR-swizzled
    char* f_b    = smem + 49152;         // 16 KB f16, XOR-swizzled
    char* h_b    = smem + 65536;         // 16 KB f16, XOR-swizzled

    const int t = threadIdx.x;
    const int lane = t & 63;
    const int wv = t >> 6;           // wave 0..7
    const int l15 = lane & 15;
    const int lg = lane >> 4;        // 0..3
    const int ch = 16 * wv + l15;    // this lane's output channel (16/wave)

    // Weight fragments: ONE 16-ch slice per wave, both layers = 32 VGPRs.
    // B-frag: col = lane&15, k = (lane>>4)*8 + j.
    f16x8 w1f[4], w2f[4];
#pragma unroll
    for (int s = 0; s < 4; ++s) {
        f16x8 a, b;
#pragma unroll
        for (int j = 0; j < 8; ++j) {
            const int k = s * 32 + lg * 8 + j;
            a[j] = (f16)W1g[k * C + ch];
            b[j] = (f16)W2g[k * C + ch];
        }
        w1f[s] = a;
        w2f[s] = b;
    }
    const float b1v = b1g[ch];
    const float b2v = b2g[ch];

    // Staging: thread covers point sp, channels sc..sc+15 (8 threads/point).
    const int sp = t >> 3;
    const int sc = (t & 7) * 16;
    const long long step = (long long)gridDim.x * PTS;
    const long long base0 = (long long)blockIdx.x * PTS;

    // ---- Prologue: DMA tile 0's feats slice; sync idx for tile 0 ---------
    int vnx;
    {
        const long long p = base0 + sp;
        const long long pc = (p < n) ? p : (long long)(n - 1);
        const char* fs = (const char*)(feats + (size_t)pc * C + sc);
#pragma unroll
        for (int c = 0; c < 4; ++c) gll16(fs + c * 16, fstage + c * 8192 + t * 16);
        vnx = (p < n) ? idx[p] : 0;
    }

    for (long long base = base0; base < n; base += step) {
        // ---- Wait DMA; stage os/f from fstage + pooled[vnx] --------------
        asm volatile("s_waitcnt vmcnt(0)" ::: "memory");
        {
            const bool valid = (base + sp) < n;
            union { uint4 u[4]; float f[16]; } ff;
#pragma unroll
            for (int c = 0; c < 4; ++c)
                ff.u[c] = *reinterpret_cast<const uint4*>(fstage + c * 8192 + t * 16);
            union { uint4 u[2]; __half h[16]; } pl;
            if (valid) {
                const uint4* pp = reinterpret_cast<const uint4*>(pooled + (size_t)vnx * C + sc);
                pl.u[0] = pp[0];
                pl.u[1] = pp[1];
            } else {
                pl.u[0] = make_uint4(0, 0, 0, 0);
                pl.u[1] = make_uint4(0, 0, 0, 0);
            }
            union { uint4 u[2]; f16 h[16]; } osv, fvh;
#pragma unroll
            for (int j = 0; j < 16; ++j) {
                const float fj = valid ? ff.f[j] : 0.f;
                osv.h[j] = (f16)(fj - __half2float(pl.h[j]));
                fvh.h[j] = (f16)fj;
            }
#pragma unroll
            for (int u = 0; u < 2; ++u) {
                const int byte = (sp * 256 + (sc + u * 8) * 2) ^ ((sp & 7) << 4);
                *reinterpret_cast<uint4*>(os_b + byte) = osv.u[u];
                *reinterpret_cast<uint4*>(f_b + byte) = fvh.u[u];
            }
        }
        __builtin_amdgcn_sched_barrier(0);  // keep GLL below the fstage reads

        // ---- Issue DMA for tile i+1; prefetch its idx (1 reg) ------------
        if (base + step < n) {  // block-uniform guard
            const long long pn = base + step + sp;
            const long long pc = (pn < n) ? pn : (long long)(n - 1);
            const char* fs = (const char*)(feats + (size_t)pc * C + sc);
#pragma unroll
            for (int c = 0; c < 4; ++c) gll16(fs + c * 16, fstage + c * 8192 + t * 16);
            vnx = (pn < n) ? idx[pn] : 0;
        }
        bar_lds();  // bar1: os/f staged (DMA + idx stay in flight)

        // ---- Layer 1: acc = os @ W1 + b1 (16 MFMA/wave) ------------------
        f32x4 acc[4];
#pragma unroll
        for (int q = 0; q < 4; ++q)
            acc[q] = (f32x4){b1v, b1v, b1v, b1v};

#pragma unroll
        for (int s = 0; s < 4; ++s) {
            f16x8 af[4];
#pragma unroll
            for (int q = 0; q < 4; ++q) {
                const int p = q * 16 + l15;
                const int byte = (p * 256 + (s * 32 + lg * 8) * 2) ^ ((p & 7) << 4);
                U16 tmp;
                tmp.u = *reinterpret_cast<const uint4*>(os_b + byte);
                af[q] = tmp.h;
            }
#pragma unroll
            for (int q = 0; q < 4; ++q)
                acc[q] = __builtin_amdgcn_mfma_f32_16x16x32_f16(af[q], w1f[s], acc[q], 0, 0, 0);
        }

        // ---- h = relu(acc) * f -> h_b (own 16-ch slice, all 64 pts) ------
        // C/D layout: col = lane&15 (channel), row = (lane>>4)*4 + reg (point)
#pragma unroll
        for (int q = 0; q < 4; ++q)
#pragma unroll
            for (int r = 0; r < 4; ++r) {
                const int d = q * 16 + lg * 4 + r;
                const int byte = (d * 256 + ch * 2) ^ ((d & 7) << 4);
                const float fval = (float)*reinterpret_cast<const f16*>(f_b + byte);
                const float hv = fmaxf(acc[q][r], 0.f) * fval;
                *reinterpret_cast<f16*>(h_b + byte) = (f16)hv;
            }
        bar_lds();  // bar2: h complete (and all os/f reads done)

        // ---- Layer 2: out = relu(h @ W2 + b2) ----------------------------
        f32x4 acc2[4];
#pragma unroll
        for (int q = 0; q < 4; ++q)
            acc2[q] = (f32x4){b2v, b2v, b2v, b2v};

#pragma unroll
        for (int s = 0; s < 4; ++s) {
            f16x8 af[4];
#pragma unroll
            for (int q = 0; q < 4; ++q) {
                const int p = q * 16 + l15;
                const int byte = (p * 256 + (s * 32 + lg * 8) * 2) ^ ((p & 7) << 4);
                U16 tmp;
                tmp.u = *reinterpret_cast<const uint4*>(h_b + byte);
                af[q] = tmp.h;
            }
#pragma unroll
            for (int q = 0; q < 4; ++q)
                acc2[q] = __builtin_amdgcn_mfma_f32_16x16x32_f16(af[q], w2f[s], acc2[q], 0, 0, 0);
        }

#pragma unroll
        for (int q = 0; q < 4; ++q)
#pragma unroll
            for (int r = 0; r < 4; ++r) {
                const int d = q * 16 + lg * 4 + r;
                const long long gp = base + d;
                if (gp < n)
                    out[gp * C + ch] = fmaxf(acc2[q][r], 0.f);
            }
        // No 3rd barrier: next stage writes os/f only; live h_b reads belong
        // to threads that must pass bar1(i+1) before h is rewritten.
    }
}

// -------------------------------------------------------------------------
// Launch
// -------------------------------------------------------------------------
extern "C" void kernel_launch(void* const* d_in, const int* in_sizes, int n_in,
                              void* d_out, int out_size, void* d_ws, size_t ws_size,
                              hipStream_t stream) {
    const float* feats = (const float*)d_in[0];
    const float* W1    = (const float*)d_in[1];
    const float* b1    = (const float*)d_in[2];
    const float* W2    = (const float*)d_in[3];
    const float* b2    = (const float*)d_in[4];
    const int*   idx   = (const int*)d_in[5];
    float*       out   = (float*)d_out;

    const int n = in_sizes[5];

    // Workspace: cnt[V] int | bucket[V*64] int | pooled[V*C] f16
    int* cnt    = (int*)d_ws;
    int* bucket = cnt + V;
    __half* pooled = (__half*)(bucket + (size_t)V * BKT);

    zero_cnt<<<V / (256 * 4), 256, 0, stream>>>((int4*)cnt);
    bucket_scatter<<<(n + 255) / 256, 256, 0, stream>>>(idx, cnt, bucket, n);
    pool_bucket<<<V / 4, 256, 0, stream>>>(feats, bucket, cnt, pooled);

    hipFuncSetAttribute((const void*)mlp_mfma,
                        hipFuncAttributeMaxDynamicSharedMemorySize,
                        (int)MLP_LDS);
    mlp_mfma<<<512, MLP_BLOCK, MLP_LDS, stream>>>(feats, W1, b1, W2, b2, idx,
                                                  pooled, out, n);
}

// Round 18
// 203.686 us; speedup vs baseline: 1.1677x; 1.1677x over previous
//
#include <hip/hip_runtime.h>
#include <hip/hip_fp16.h>

typedef _Float16 f16;
typedef _Float16 f16x8 __attribute__((ext_vector_type(8)));
typedef float f32x4 __attribute__((ext_vector_type(4)));

constexpr int C = 128;        // channels
constexpr int V = 65536;      // voxels
constexpr int PTS = 64;       // points per MFMA tile
constexpr int MLP_BLOCK = 512;// 8 waves; each wave owns 16 output channels
constexpr int BKT = 64;       // bucket capacity per voxel (P(overflow) ~ 1e-26)

union U16 { uint4 u; f16x8 h; };

// -------------------------------------------------------------------------
// Kernel 0: zero the counters (rocclr's small fill kernel is latency-bound).
// -------------------------------------------------------------------------
__global__ void zero_cnt(int4* __restrict__ cnt) {
    const int t = blockIdx.x * blockDim.x + threadIdx.x;
    cnt[t] = make_int4(0, 0, 0, 0);
}

// -------------------------------------------------------------------------
// Kernel 1: bucket scatter — fixed-stride CSR, no scan needed.
// -------------------------------------------------------------------------
__global__ void bucket_scatter(const int* __restrict__ idx, int* __restrict__ cnt,
                               int* __restrict__ bucket, int n) {
    const int t = blockIdx.x * blockDim.x + threadIdx.x;
    if (t < n) {
        const int v = idx[t];
        const int slot = atomicAdd(&cnt[v], 1);
        if (slot < BKT) bucket[(v << 6) + slot] = t;
    }
}

// -------------------------------------------------------------------------
// Kernel 2: pooling — one wave per voxel; half-wave per point row, float4
// loads (32 lanes x 16B = 512B row), 2-deep unroll -> 4 rows in flight.
// -------------------------------------------------------------------------
__global__ void __launch_bounds__(256)
pool_bucket(const float* __restrict__ feats, const int* __restrict__ bucket,
            const int* __restrict__ cnt, __half* __restrict__ pooled) {
    const int v = blockIdx.x * 4 + (threadIdx.x >> 6);
    const int lane = threadIdx.x & 63;
    const int half = lane >> 5;      // 0 or 1: which point of a pair
    const int l32 = lane & 31;       // channel quad: channels l32*4..+3
    const int e = min(cnt[v], BKT);
    const int* b = bucket + (v << 6);

    f32x4 a0 = {0.f, 0.f, 0.f, 0.f};
    f32x4 a1 = {0.f, 0.f, 0.f, 0.f};
    int j = half;
    for (; j + 2 < e; j += 4) {      // handles rows j and j+2 per iter
        const int p0 = b[j];
        const int p1 = b[j + 2];
        a0 += *reinterpret_cast<const f32x4*>(feats + (size_t)p0 * C + l32 * 4);
        a1 += *reinterpret_cast<const f32x4*>(feats + (size_t)p1 * C + l32 * 4);
    }
    if (j < e) {
        const int p0 = b[j];
        a0 += *reinterpret_cast<const f32x4*>(feats + (size_t)p0 * C + l32 * 4);
    }
    a0 += a1;
#pragma unroll
    for (int c = 0; c < 4; ++c)
        a0[c] += __shfl_xor(a0[c], 32);

    if (half == 0) {
        const float rc = e ? 1.0f / (float)e : 0.f;
        const __half2 lo = __floats2half2_rn(a0[0] * rc, a0[1] * rc);
        const __half2 hi = __floats2half2_rn(a0[2] * rc, a0[3] * rc);
        union { uint2 u; __half2 h[2]; } pk;
        pk.h[0] = lo; pk.h[1] = hi;
        *reinterpret_cast<uint2*>(pooled + (size_t)v * C + l32 * 4) = pk.u;
    }
}

// -------------------------------------------------------------------------
// Kernel 3: fused gather + 2-layer MLP via f16 MFMA (16x16x32).
// R13 structure — the empirical optimum of this design space:
// 8 waves x 16 output channels (weight regs 32, VGPR < 128 cliff),
// 48 KB static LDS (2 blocks/CU -> 16 waves/CU), synchronous staging,
// 2 barriers/tile. Pipelining ledger (all regressed): reg-prefetch
// (R10/R15/R16: VGPR cliff), GLL+80KB (R17: 1 block/CU).
//   os  = feats - pooled_mean[idx]   (os_lds, f16, XOR-swizzled)
//   h   = relu(os @ W1 + b1) * f     (f from f_lds; h -> h_lds)
//   out = relu(h @ W2 + b2)
// -------------------------------------------------------------------------
__global__ void __launch_bounds__(MLP_BLOCK)
mlp_mfma(const float* __restrict__ feats,
         const float* __restrict__ W1g,
         const float* __restrict__ b1g,
         const float* __restrict__ W2g,
         const float* __restrict__ b2g,
         const int* __restrict__ idx,
         const __half* __restrict__ pooled,
         float* __restrict__ out,
         int n) {
    __shared__ f16 os_lds[PTS * C];  // 16 KB, XOR-swizzled rows
    __shared__ f16 f_lds[PTS * C];   // 16 KB
    __shared__ f16 h_lds[PTS * C];   // 16 KB

    const int t = threadIdx.x;
    const int lane = t & 63;
    const int wv = t >> 6;           // wave 0..7
    const int l15 = lane & 15;
    const int lg = lane >> 4;        // 0..3
    const int ch = 16 * wv + l15;    // this lane's output channel (16/wave)

    // Weight fragments: ONE 16-ch slice per wave, both layers = 32 VGPRs.
    // B-frag: col = lane&15, k = (lane>>4)*8 + j.
    f16x8 w1f[4], w2f[4];
#pragma unroll
    for (int s = 0; s < 4; ++s) {
        f16x8 a, b;
#pragma unroll
        for (int j = 0; j < 8; ++j) {
            const int k = s * 32 + lg * 8 + j;
            a[j] = (f16)W1g[k * C + ch];
            b[j] = (f16)W2g[k * C + ch];
        }
        w1f[s] = a;
        w2f[s] = b;
    }
    const float b1v = b1g[ch];
    const float b2v = b2g[ch];

    // Staging: thread covers point sp, channels sc..sc+15 (8 threads/point).
    const int sp = t >> 3;
    const int sc = (t & 7) * 16;

    for (long long base = (long long)blockIdx.x * PTS; base < n;
         base += (long long)gridDim.x * PTS) {
        // ---- Stage os (= f - mean) and f into LDS as f16, swizzled ------
        {
            const long long p = base + sp;
            union { float4 v4[4]; float f[16]; } ff;
            union { uint4 u[2]; __half h[16]; } pl;
            if (p < n) {
#pragma unroll
                for (int j = 0; j < 4; ++j)
                    ff.v4[j] = *reinterpret_cast<const float4*>(feats + (size_t)p * C + sc + j * 4);
                const int v = idx[p];
                const uint4* pp = reinterpret_cast<const uint4*>(pooled + (size_t)v * C + sc);
#pragma unroll
                for (int j = 0; j < 2; ++j) pl.u[j] = pp[j];
            } else {
#pragma unroll
                for (int j = 0; j < 4; ++j) ff.v4[j] = make_float4(0.f, 0.f, 0.f, 0.f);
#pragma unroll
                for (int j = 0; j < 2; ++j) pl.u[j] = make_uint4(0, 0, 0, 0);
            }
            union { uint4 u[2]; f16 h[16]; } osv, fvh;
#pragma unroll
            for (int j = 0; j < 16; ++j) {
                const float fj = ff.f[j];
                osv.h[j] = (f16)(fj - __half2float(pl.h[j]));
                fvh.h[j] = (f16)fj;
            }
#pragma unroll
            for (int u = 0; u < 2; ++u) {
                const int byte = (sp * 256 + (sc + u * 8) * 2) ^ ((sp & 7) << 4);
                *reinterpret_cast<uint4*>(reinterpret_cast<char*>(os_lds) + byte) = osv.u[u];
                *reinterpret_cast<uint4*>(reinterpret_cast<char*>(f_lds) + byte) = fvh.u[u];
            }
        }
        __syncthreads();  // bar1: os/f staged (also orders h-write vs prior L2)

        // ---- Layer 1: acc = os @ W1 + b1 (16 MFMA/wave) ------------------
        f32x4 acc[4];
#pragma unroll
        for (int q = 0; q < 4; ++q)
            acc[q] = (f32x4){b1v, b1v, b1v, b1v};

#pragma unroll
        for (int s = 0; s < 4; ++s) {
            f16x8 af[4];
#pragma unroll
            for (int q = 0; q < 4; ++q) {
                const int p = q * 16 + l15;
                const int byte = (p * 256 + (s * 32 + lg * 8) * 2) ^ ((p & 7) << 4);
                U16 tmp;
                tmp.u = *reinterpret_cast<const uint4*>(reinterpret_cast<const char*>(os_lds) + byte);
                af[q] = tmp.h;
            }
#pragma unroll
            for (int q = 0; q < 4; ++q)
                acc[q] = __builtin_amdgcn_mfma_f32_16x16x32_f16(af[q], w1f[s], acc[q], 0, 0, 0);
        }

        // ---- h = relu(acc) * f -> h_lds (own 16-ch slice, all 64 pts) ----
        // C/D layout: col = lane&15 (channel), row = (lane>>4)*4 + reg (point)
#pragma unroll
        for (int q = 0; q < 4; ++q)
#pragma unroll
            for (int r = 0; r < 4; ++r) {
                const int d = q * 16 + lg * 4 + r;
                const int byte = (d * 256 + ch * 2) ^ ((d & 7) << 4);
                const float fval = (float)*reinterpret_cast<const f16*>(
                    reinterpret_cast<const char*>(f_lds) + byte);
                const float hv = fmaxf(acc[q][r], 0.f) * fval;
                *reinterpret_cast<f16*>(reinterpret_cast<char*>(h_lds) + byte) = (f16)hv;
            }
        __syncthreads();  // bar2: h complete (and all os/f reads done)

        // ---- Layer 2: out = relu(h @ W2 + b2) ----------------------------
        f32x4 acc2[4];
#pragma unroll
        for (int q = 0; q < 4; ++q)
            acc2[q] = (f32x4){b2v, b2v, b2v, b2v};

#pragma unroll
        for (int s = 0; s < 4; ++s) {
            f16x8 af[4];
#pragma unroll
            for (int q = 0; q < 4; ++q) {
                const int p = q * 16 + l15;
                const int byte = (p * 256 + (s * 32 + lg * 8) * 2) ^ ((p & 7) << 4);
                U16 tmp;
                tmp.u = *reinterpret_cast<const uint4*>(reinterpret_cast<const char*>(h_lds) + byte);
                af[q] = tmp.h;
            }
#pragma unroll
            for (int q = 0; q < 4; ++q)
                acc2[q] = __builtin_amdgcn_mfma_f32_16x16x32_f16(af[q], w2f[s], acc2[q], 0, 0, 0);
        }

#pragma unroll
        for (int q = 0; q < 4; ++q)
#pragma unroll
            for (int r = 0; r < 4; ++r) {
                const int d = q * 16 + lg * 4 + r;
                const long long gp = base + d;
                if (gp < n)
                    out[gp * C + ch] = fmaxf(acc2[q][r], 0.f);
            }
        // No 3rd barrier: next stage writes os/f only; the live h_lds reads
        // belong to threads that must pass bar1(i+1) before h is rewritten.
    }
}

// -------------------------------------------------------------------------
// Launch
// -------------------------------------------------------------------------
extern "C" void kernel_launch(void* const* d_in, const int* in_sizes, int n_in,
                              void* d_out, int out_size, void* d_ws, size_t ws_size,
                              hipStream_t stream) {
    const float* feats = (const float*)d_in[0];
    const float* W1    = (const float*)d_in[1];
    const float* b1    = (const float*)d_in[2];
    const float* W2    = (const float*)d_in[3];
    const float* b2    = (const float*)d_in[4];
    const int*   idx   = (const int*)d_in[5];
    float*       out   = (float*)d_out;

    const int n = in_sizes[5];

    // Workspace: cnt[V] int | bucket[V*64] int | pooled[V*C] f16
    int* cnt    = (int*)d_ws;
    int* bucket = cnt + V;
    __half* pooled = (__half*)(bucket + (size_t)V * BKT);

    zero_cnt<<<V / (256 * 4), 256, 0, stream>>>((int4*)cnt);
    bucket_scatter<<<(n + 255) / 256, 256, 0, stream>>>(idx, cnt, bucket, n);
    pool_bucket<<<V / 4, 256, 0, stream>>>(feats, bucket, cnt, pooled);
    mlp_mfma<<<512, MLP_BLOCK, 0, stream>>>(feats, W1, b1, W2, b2, idx,
                                            pooled, out, n);
}